// Round 6
// baseline (757.440 us; speedup 1.0000x reference)
//
#include <hip/hip_runtime.h>
#include <hip/hip_bf16.h>
#include <cstdint>
#include <cstddef>

// ---------------------------------------------------------------------------
// CausalSelfAttention: x[2,4096,768] fp32, W_qkv[768,2304], b_qkv, W_proj[768,768], b_proj
// bf16 MFMA. All staging via __builtin_amdgcn_global_load_lds(16B) with
// XOR-swizzled source chunks. Attention: persistent 4-wave blocks + atomic
// queue; P stays in registers via mfma_16x16x16bf16_1k.
// R4: never hold staging loads in VGPRs across compute (spills).
// R6: LDS staging is mandatory for 4-wave-reused operands.
// R7: dbuf + counted vmcnt prefetch = NEUTRAL (TLP already hides it).
// R8: removing the mid-tile barrier = REGRESSION. Lockstep is right.
// R9: 128-key tiles = REGRESSION (VGPR 148, occupancy 16->11).
// R10: 64-row items = REGRESSION (staging per unit compute doubled).
// R11: VALU diet = NEUTRAL on attn (not VALU-issue-bound); proj 128x64 +
//      merged wtrans banked ~5us. Calibration: per-SIMD busy only ~25-30%.
// R12 (this round): attn is latency-idle at grid-limited 3 blocks/CU.
// KEY-SPLIT items (flash-decoding): item = (bh, 128-row qblock, key-half).
// Staging:compute ratio UNCHANGED (halves partition the key range) unlike
// R10. 1512 items -> 4 blocks/CU (VGPR-capped via launch_bounds(256,4)).
// Fixed-max softmax => partials merge by ADDITION: each half stores
// O^T/lsum fp32 partials to its own slot (agent-scope atomics), fence,
// atomicAdd arrival flag; SECOND arrival merges in-register and writes An.
// No spin, no extra kernel, deadlock-free (first never blocks).
// ---------------------------------------------------------------------------

typedef __attribute__((ext_vector_type(8))) short bf16x8;   // 8 bf16 = 4 VGPRs
typedef __attribute__((ext_vector_type(4))) short bf16x4;   // 4 bf16 = 2 VGPRs
typedef __attribute__((ext_vector_type(4))) float f32x4;

#define MFMA16(a, b, c)   __builtin_amdgcn_mfma_f32_16x16x32_bf16((a), (b), (c), 0, 0, 0)
#define MFMA16K(a, b, c)  __builtin_amdgcn_mfma_f32_16x16x16bf16_1k((a), (b), (c), 0, 0, 0)

static constexpr int Bc = 2, Tc = 4096, Dc = 768, Hc = 12, DKc = 64;
static constexpr int BHc = Bc * Hc;      // 24
static constexpr int Mc = Bc * Tc;       // 8192
static constexpr int Nqkv = 3 * Dc;      // 2304
static constexpr int NQBLK = Tc / 128;   // 32 Q-blocks per bh
// key-split items: qb=1..31 split into 2 halves (24*31*2=1488) + 24 singles
static constexpr unsigned int NSPLIT = 24u * 31u * 2u;   // 1488
static constexpr unsigned int NIT = NSPLIT + 24u;        // 1512
static constexpr int NPAIR = 31 * 24;                    // 744 merge pairs

__device__ __forceinline__ unsigned short f2bf(float f) {
    union { float f; unsigned int i; } c; c.f = f;
    unsigned int x = c.i;
    return (unsigned short)((x + 0x7fffu + ((x >> 16) & 1u)) >> 16); // RNE
}
__device__ __forceinline__ unsigned int pkbf(float a, float b) {
    __hip_bfloat162 h = __float22bfloat162_rn(make_float2(a, b));   // v_cvt_pk_bf16_f32
    union { __hip_bfloat162 h; unsigned int u; } c; c.h = h;
    return c.u;
}
// async global->LDS, 16B per lane; LDS dest = wave-uniform base + lane*16
__device__ __forceinline__ void glds16(const unsigned short* g, unsigned short* l) {
    __builtin_amdgcn_global_load_lds(
        (const __attribute__((address_space(1))) unsigned int*)g,
        (__attribute__((address_space(3))) unsigned int*)l, 16, 0, 0);
}

// ---------------------------------------------------------------------------
// x fp32 -> bf16, flat copy.
// ---------------------------------------------------------------------------
__global__ __launch_bounds__(256)
void xconv_kernel(const float* __restrict__ X, unsigned short* __restrict__ Xb) {
    size_t i = ((size_t)blockIdx.x * 256 + threadIdx.x) * 8;
    float4 a = *(const float4*)(X + i);
    float4 b = *(const float4*)(X + i + 4);
    uint4 o;
    o.x = pkbf(a.x, a.y); o.y = pkbf(a.z, a.w);
    o.z = pkbf(b.x, b.y); o.w = pkbf(b.z, b.w);
    *(uint4*)(Xb + i) = o;
}

// ---------------------------------------------------------------------------
// W [768][N] fp32 -> WT [N][768] bf16, both weight matrices in ONE launch.
// grid (12, 48): y<36 -> W_qkv (N=2304), else W_proj (N=768). 256 thr.
// ---------------------------------------------------------------------------
__global__ __launch_bounds__(256)
void wtrans_kernel(const float* __restrict__ Wq, const float* __restrict__ Wp,
                   unsigned short* __restrict__ WqT, unsigned short* __restrict__ WpT) {
    __shared__ __align__(16) unsigned short tile[64 * 72];
    const int k0 = blockIdx.x * 64;
    const int yb = blockIdx.y;
    const float* W;
    unsigned short* WT;
    int N, n0;
    if (yb < 36) { W = Wq; WT = WqT; N = Nqkv; n0 = yb * 64; }
    else         { W = Wp; WT = WpT; N = Dc;   n0 = (yb - 36) * 64; }
    const int tid = threadIdx.x;
#pragma unroll
    for (int it = 0; it < 4; ++it) {
        int s = tid + it * 256;
        int r = s >> 4, g = s & 15;
        float4 v = *(const float4*)(W + (size_t)(k0 + r) * N + n0 + g * 4);
        ushort4 u;
        u.x = f2bf(v.x); u.y = f2bf(v.y); u.z = f2bf(v.z); u.w = f2bf(v.w);
        *(ushort4*)(tile + r * 72 + g * 4) = u;
    }
    __syncthreads();
#pragma unroll
    for (int it = 0; it < 2; ++it) {
        int s = tid + it * 256;
        int n = s >> 3, g = s & 7;
        unsigned int p0 = (unsigned int)tile[(g * 8 + 0) * 72 + n] |
                          ((unsigned int)tile[(g * 8 + 1) * 72 + n] << 16);
        unsigned int p1 = (unsigned int)tile[(g * 8 + 2) * 72 + n] |
                          ((unsigned int)tile[(g * 8 + 3) * 72 + n] << 16);
        unsigned int p2 = (unsigned int)tile[(g * 8 + 4) * 72 + n] |
                          ((unsigned int)tile[(g * 8 + 5) * 72 + n] << 16);
        unsigned int p3 = (unsigned int)tile[(g * 8 + 6) * 72 + n] |
                          ((unsigned int)tile[(g * 8 + 7) * 72 + n] << 16);
        uint4 o; o.x = p0; o.y = p1; o.z = p2; o.w = p3;
        *(uint4*)(WT + (size_t)(n0 + n) * Dc + k0 + g * 8) = o;
    }
}

// ---------------------------------------------------------------------------
// QKV GEMM: Xb[8192][768] bf16 x WqT[2304][768] bf16 (+bias) -> Q/K [bh][t][dk],
// V transposed to Vt [bh][dk][t]. Q pre-scaled by 0.125*log2(e).
// BK=64, global_load_lds staging, XOR-swizzled chunks. grid (64,18).
// ---------------------------------------------------------------------------
__global__ __launch_bounds__(256)
void qkv_gemm_kernel(const unsigned short* __restrict__ Xb,
                     const unsigned short* __restrict__ WT,
                     const float* __restrict__ bias,
                     unsigned short* __restrict__ Qb, unsigned short* __restrict__ Kb,
                     unsigned short* __restrict__ Vt) {
    __shared__ __align__(16) unsigned short As[128 * 64];  // [row][64K], swizzled
    __shared__ __align__(16) unsigned short Bs[128 * 64];
    const int tid = threadIdx.x;
    const int wave = tid >> 6, lane = tid & 63;
    const int quad = lane >> 4, l15 = lane & 15;
    const int wr = wave >> 1, wc = wave & 1;
    const int r0 = blockIdx.x * 128, c0 = blockIdx.y * 128;
    const int sw = l15 & 7;   // fragment-read swizzle key (row&7 == l15&7)

    f32x4 acc[4][4];
#pragma unroll
    for (int i = 0; i < 4; ++i)
#pragma unroll
        for (int j = 0; j < 4; ++j) acc[i][j] = (f32x4){0.f, 0.f, 0.f, 0.f};

    for (int k0 = 0; k0 < Dc; k0 += 64) {
#pragma unroll
        for (int it = 0; it < 4; ++it) {      // stage 128x64 A and B tiles
            int idx = it * 256 + tid;
            int r = idx >> 3, c = idx & 7;
            int cg = c ^ (r & 7);             // LDS slot c holds global chunk cg
            glds16(Xb + (size_t)(r0 + r) * Dc + k0 + cg * 8, As + idx * 8);
            glds16(WT + (size_t)(c0 + r) * Dc + k0 + cg * 8, Bs + idx * 8);
        }
        __syncthreads();
#pragma unroll
        for (int f = 0; f < 2; ++f) {
            bf16x8 af[4], bfr[4];
#pragma unroll
            for (int mt = 0; mt < 4; ++mt)
                af[mt] = *(const bf16x8*)(As + (wr * 64 + mt * 16 + l15) * 64 +
                                          (((f * 4 + quad) ^ sw) * 8));
#pragma unroll
            for (int nt = 0; nt < 4; ++nt)
                bfr[nt] = *(const bf16x8*)(Bs + (wc * 64 + nt * 16 + l15) * 64 +
                                           (((f * 4 + quad) ^ sw) * 8));
#pragma unroll
            for (int mt = 0; mt < 4; ++mt)
#pragma unroll
                for (int nt = 0; nt < 4; ++nt)
                    acc[mt][nt] = MFMA16(af[mt], bfr[nt], acc[mt][nt]);
        }
        __syncthreads();
    }

    const int part = c0 / Dc;
    const int cbase = c0 - part * Dc;
    const float scale = (part == 0) ? 0.125f * 1.4426950408889634f : 1.0f;
    float bv[4];
#pragma unroll
    for (int nt = 0; nt < 4; ++nt) bv[nt] = bias[c0 + wc * 64 + nt * 16 + l15];

    if (part < 2) {
        unsigned short* dstbuf = (part == 0) ? Qb : Kb;
#pragma unroll
        for (int mt = 0; mt < 4; ++mt)
#pragma unroll
            for (int reg = 0; reg < 4; ++reg) {
                int gr = r0 + wr * 64 + mt * 16 + quad * 4 + reg;
                int b = gr >> 12, t = gr & 4095;
#pragma unroll
                for (int nt = 0; nt < 4; ++nt) {
                    int cc = cbase + wc * 64 + nt * 16 + l15;
                    int h = cc >> 6, dk = cc & 63;
                    float v = (acc[mt][nt][reg] + bv[nt]) * scale;
                    dstbuf[((size_t)(b * Hc + h) * Tc + t) * DKc + dk] = f2bf(v);
                }
            }
    } else {
        // V: write transposed [bh][dk][t]
#pragma unroll
        for (int mt = 0; mt < 4; ++mt)
#pragma unroll
            for (int reg = 0; reg < 4; ++reg) {
                int gr = r0 + wr * 64 + mt * 16 + quad * 4 + reg;
                int b = gr >> 12, t = gr & 4095;
#pragma unroll
                for (int nt = 0; nt < 4; ++nt) {
                    int cc = cbase + wc * 64 + nt * 16 + l15;
                    int h = cc >> 6, dk = cc & 63;
                    float v = acc[mt][nt][reg] + bv[nt];
                    Vt[((size_t)(b * Hc + h) * DKc + dk) * Tc + t] = f2bf(v);
                }
            }
    }
}

// ---------------------------------------------------------------------------
// Flash attention, key-split: 1512 items via atomic queue, longest first.
//   w < 1488: qb = 31 - w/48, bh = (w%48)>>1, half = w&1 -> tiles
//             [half*T, half*T+T) of 64 keys, T = qb+1. half 0 never masks.
//   else:     single item qb=0, tiles {0,1}, both masked.
// Per 64-key tile: EXACT R0 lockstep (stage -> sync -> frags -> lgkm+barrier
// EARLY -> QK(czero) -> mask? -> exp2/pack -> lsum,PV via MFMA).
// Split epilogue: store my O^T/lsum fp32 partials to slot[pid][half]
// (agent-scope relaxed atomics) -> threadfence -> syncthreads -> tid0
// atomicAdd(flags[pid]); if I'm SECOND (ret==1): threadfence, load partner
// partials, add in-register, normalize by combined lsum, write bf16 An.
// ---------------------------------------------------------------------------
__global__ __launch_bounds__(256, 4)
void attn_kernel(const unsigned short* __restrict__ Qb,
                 const unsigned short* __restrict__ Kb,
                 const unsigned short* __restrict__ Vt,
                 unsigned short* __restrict__ attn,
                 unsigned int* __restrict__ counter,
                 unsigned int* __restrict__ flags,
                 float* __restrict__ Opart,
                 float* __restrict__ Lpart) {
    __shared__ __align__(16) unsigned short Ks[64 * 64];   // [key][dk] swizzled
    __shared__ __align__(16) unsigned short Vs[64 * 64];   // [dk][key] swizzled
    __shared__ unsigned int s_w, s_role;
    const int tid = threadIdx.x;
    const int wave = tid >> 6, lane = tid & 63;
    const int quad = lane >> 4, l15 = lane & 15;
    const int sw = l15 & 7;
    const f32x4 czero = (f32x4){0.f, 0.f, 0.f, 0.f};
    const bf16x4 ones = (bf16x4){(short)0x3F80, (short)0x3F80,
                                 (short)0x3F80, (short)0x3F80};  // bf16 1.0 x4

    for (;;) {
        if (tid == 0) s_w = atomicAdd(counter, 1u);
        __syncthreads();
        const unsigned int w = s_w;
        if (w >= NIT) break;
        int qb, bh, half;
        bool split;
        if (w < NSPLIT) {
            int g = (int)(w / 48u);
            int r = (int)(w - (unsigned)g * 48u);
            qb = 31 - g; bh = r >> 1; half = r & 1; split = true;
        } else {
            bh = (int)(w - NSPLIT); qb = 0; half = 0; split = false;
        }
        const int T = qb + 1;
        const int i0 = qb * 128;
        const int jbeg = split ? half * T : 0;
        const int jend = split ? jbeg + T : 2;

        const unsigned short* Qp = Qb + (size_t)bh * Tc * DKc;
        const unsigned short* Kp = Kb + (size_t)bh * Tc * DKc;
        const unsigned short* Vp = Vt + (size_t)bh * DKc * Tc;

        // Q fragments for this wave's 32 rows (pre-scaled 0.125*log2e)
        bf16x8 qf[2][2];
#pragma unroll
        for (int qg = 0; qg < 2; ++qg)
#pragma unroll
            for (int f = 0; f < 2; ++f)
                qf[qg][f] = *(const bf16x8*)(Qp +
                    (size_t)(i0 + wave * 32 + qg * 16 + l15) * DKc + f * 32 + quad * 8);

        f32x4 lsum[2] = {czero, czero};
        f32x4 o[2][4];
#pragma unroll
        for (int qg = 0; qg < 2; ++qg)
#pragma unroll
            for (int d = 0; d < 4; ++d) o[qg][d] = (f32x4){0.f, 0.f, 0.f, 0.f};

        for (int jt = jbeg; jt < jend; ++jt) {
            const int j0 = jt * 64;
#pragma unroll
            for (int it = 0; it < 2; ++it) {               // async staging, swizzled
                int idx = it * 256 + tid;
                int r = idx >> 3, c = idx & 7;
                int cg = c ^ (r & 7);
                glds16(Kp + (size_t)(j0 + r) * DKc + cg * 8, Ks + idx * 8);
                glds16(Vp + (size_t)r * Tc + j0 + cg * 8, Vs + idx * 8);
            }
            __syncthreads();

            // fragments -> regs; then barrier EARLY so next staging can begin
            bf16x8 kf[2][4];
            bf16x4 vf[4][4];
#pragma unroll
            for (int f = 0; f < 2; ++f)
#pragma unroll
                for (int mt = 0; mt < 4; ++mt)
                    kf[f][mt] = *(const bf16x8*)(Ks + (mt * 16 + l15) * 64 +
                                                 (((f * 4 + quad) ^ sw) * 8));
#pragma unroll
            for (int d = 0; d < 4; ++d)
#pragma unroll
                for (int mt = 0; mt < 4; ++mt) {
                    int g8 = mt * 4 + quad;
                    vf[d][mt] = *(const bf16x4*)(Vs + (d * 16 + l15) * 64 +
                                                 (((g8 >> 1) ^ sw) * 8) + (g8 & 1) * 4);
                }
            asm volatile("s_waitcnt lgkmcnt(0)" ::: "memory");
            __builtin_amdgcn_s_barrier();

            // S^T: C-layout key=16mt+quad*4+reg, q=l15; czero folds the init
            f32x4 sc[2][4];
#pragma unroll
            for (int mt = 0; mt < 4; ++mt) {
                sc[0][mt] = MFMA16(kf[0][mt], qf[0][0], czero);
                sc[1][mt] = MFMA16(kf[0][mt], qf[1][0], czero);
            }
#pragma unroll
            for (int mt = 0; mt < 4; ++mt) {
                sc[0][mt] = MFMA16(kf[1][mt], qf[0][1], sc[0][mt]);
                sc[1][mt] = MFMA16(kf[1][mt], qf[1][1], sc[1][mt]);
            }

            if (jt >= 2 * T - 2) {                         // diagonal region
                const int rel = j0 - i0;
#pragma unroll
                for (int qg = 0; qg < 2; ++qg) {
                    int qrow = wave * 32 + qg * 16 + l15;
#pragma unroll
                    for (int mt = 0; mt < 4; ++mt)
#pragma unroll
                        for (int reg = 0; reg < 4; ++reg)
                            if (rel + mt * 16 + quad * 4 + reg > qrow)
                                sc[qg][mt][reg] = -1e30f;
                }
            }

            // exp2 + pack P^T (B-operand, in-register)
            union { uint2 u; bf16x4 v; } pb[2][4];
#pragma unroll
            for (int qg = 0; qg < 2; ++qg)
#pragma unroll
                for (int mt = 0; mt < 4; ++mt) {
#pragma unroll
                    for (int reg = 0; reg < 4; ++reg)
                        sc[qg][mt][reg] = __builtin_amdgcn_exp2f(sc[qg][mt][reg]);
                    pb[qg][mt].u.x = pkbf(sc[qg][mt][0], sc[qg][mt][1]);
                    pb[qg][mt].u.y = pkbf(sc[qg][mt][2], sc[qg][mt][3]);
                }

            // lsum += colsum(P^T) (= rowsum for q=l15); O^T += V^T P^T
#pragma unroll
            for (int mt = 0; mt < 4; ++mt) {
                lsum[0] = MFMA16K(ones, pb[0][mt].v, lsum[0]);
                lsum[1] = MFMA16K(ones, pb[1][mt].v, lsum[1]);
#pragma unroll
                for (int d = 0; d < 4; ++d) {
                    o[0][d] = MFMA16K(vf[d][mt], pb[0][mt].v, o[0][d]);
                    o[1][d] = MFMA16K(vf[d][mt], pb[1][mt].v, o[1][d]);
                }
            }
        }

        const int b = bh / Hc, h = bh % Hc;
        if (!split) {
            // direct normalize + store
#pragma unroll
            for (int qg = 0; qg < 2; ++qg) {
                float li = 1.0f / lsum[qg][0];
                int t = i0 + wave * 32 + qg * 16 + l15;
                unsigned short* dst = attn + (size_t)(b * Tc + t) * Dc + h * 64;
#pragma unroll
                for (int d = 0; d < 4; ++d) {
                    uint2 u;
                    u.x = pkbf(o[qg][d][0] * li, o[qg][d][1] * li);
                    u.y = pkbf(o[qg][d][2] * li, o[qg][d][3] * li);
                    *(uint2*)(dst + d * 16 + quad * 4) = u;
                }
            }
        } else {
            const int pid = (qb - 1) * 24 + bh;
            float* Ob = Opart + ((size_t)pid * 2 + half) * (64 * 128);
            float* Lb = Lpart + ((size_t)pid * 2 + half) * 128;
            // store my partials to my half-slot (agent-scope, cache-bypassing)
#pragma unroll
            for (int qg = 0; qg < 2; ++qg) {
                int row = wave * 32 + qg * 16 + l15;
#pragma unroll
                for (int d = 0; d < 4; ++d)
#pragma unroll
                    for (int reg = 0; reg < 4; ++reg)
                        __hip_atomic_store(&Ob[(d * 16 + quad * 4 + reg) * 128 + row],
                                           o[qg][d][reg], __ATOMIC_RELAXED,
                                           __HIP_MEMORY_SCOPE_AGENT);
                if (quad == 0)
                    __hip_atomic_store(&Lb[row], lsum[qg][0], __ATOMIC_RELAXED,
                                       __HIP_MEMORY_SCOPE_AGENT);
            }
            __threadfence();
            __syncthreads();          // all threads' stores drained (vmcnt 0)
            if (tid == 0) s_role = atomicAdd(&flags[pid], 1u);
            __syncthreads();
            if (s_role == 1u) {       // I'm second: partner's partials visible
                __threadfence();
                const float* Po = Opart + ((size_t)pid * 2 + (half ^ 1)) * (64 * 128);
                const float* Pl = Lpart + ((size_t)pid * 2 + (half ^ 1)) * 128;
#pragma unroll
                for (int qg = 0; qg < 2; ++qg) {
                    int row = wave * 32 + qg * 16 + l15;
                    float pl = __hip_atomic_load(&Pl[row], __ATOMIC_RELAXED,
                                                 __HIP_MEMORY_SCOPE_AGENT);
#pragma unroll
                    for (int d = 0; d < 4; ++d)
#pragma unroll
                        for (int reg = 0; reg < 4; ++reg)
                            o[qg][d][reg] += __hip_atomic_load(
                                &Po[(d * 16 + quad * 4 + reg) * 128 + row],
                                __ATOMIC_RELAXED, __HIP_MEMORY_SCOPE_AGENT);
                    float li = 1.0f / (lsum[qg][0] + pl);
                    int t = i0 + row;
                    unsigned short* dst = attn + (size_t)(b * Tc + t) * Dc + h * 64;
#pragma unroll
                    for (int d = 0; d < 4; ++d) {
                        uint2 u;
                        u.x = pkbf(o[qg][d][0] * li, o[qg][d][1] * li);
                        u.y = pkbf(o[qg][d][2] * li, o[qg][d][3] * li);
                        *(uint2*)(dst + d * 16 + quad * 4) = u;
                    }
                }
            }
        }
    }
}

// ---------------------------------------------------------------------------
// Proj GEMM: A[8192][768] bf16 x WpT[768][768] bf16 (+bias) -> out fp32
// 128x64 tiles, BK=64: grid (64,12) = 768 blocks = 3/CU exact (no tail).
// ---------------------------------------------------------------------------
__global__ __launch_bounds__(256)
void proj_gemm_kernel(const unsigned short* __restrict__ A,
                      const unsigned short* __restrict__ WT,
                      const float* __restrict__ bias, float* __restrict__ out) {
    __shared__ __align__(16) unsigned short As[128 * 64];
    __shared__ __align__(16) unsigned short Bs[64 * 64];
    const int tid = threadIdx.x;
    const int wave = tid >> 6, lane = tid & 63;
    const int quad = lane >> 4, l15 = lane & 15;
    const int wr = wave >> 1, wc = wave & 1;
    const int r0 = blockIdx.x * 128, c0 = blockIdx.y * 64;
    const int sw = l15 & 7;

    f32x4 acc[4][2];
#pragma unroll
    for (int i = 0; i < 4; ++i)
#pragma unroll
        for (int j = 0; j < 2; ++j) acc[i][j] = (f32x4){0.f, 0.f, 0.f, 0.f};

    for (int k0 = 0; k0 < Dc; k0 += 64) {
#pragma unroll
        for (int it = 0; it < 4; ++it) {      // A: 128 rows x 8 chunks
            int idx = it * 256 + tid;
            int r = idx >> 3, c = idx & 7;
            glds16(A + (size_t)(r0 + r) * Dc + k0 + ((c ^ (r & 7)) * 8), As + idx * 8);
        }
#pragma unroll
        for (int it = 0; it < 2; ++it) {      // B: 64 rows x 8 chunks
            int idx = it * 256 + tid;
            int r = idx >> 3, c = idx & 7;
            glds16(WT + (size_t)(c0 + r) * Dc + k0 + ((c ^ (r & 7)) * 8), Bs + idx * 8);
        }
        __syncthreads();
#pragma unroll
        for (int f = 0; f < 2; ++f) {
            bf16x8 af[4], bfr[2];
#pragma unroll
            for (int mt = 0; mt < 4; ++mt)
                af[mt] = *(const bf16x8*)(As + (wr * 64 + mt * 16 + l15) * 64 +
                                          (((f * 4 + quad) ^ sw) * 8));
#pragma unroll
            for (int nt = 0; nt < 2; ++nt)
                bfr[nt] = *(const bf16x8*)(Bs + (wc * 32 + nt * 16 + l15) * 64 +
                                           (((f * 4 + quad) ^ sw) * 8));
#pragma unroll
            for (int mt = 0; mt < 4; ++mt)
#pragma unroll
                for (int nt = 0; nt < 2; ++nt)
                    acc[mt][nt] = MFMA16(af[mt], bfr[nt], acc[mt][nt]);
        }
        __syncthreads();
    }

    float bv[2];
#pragma unroll
    for (int nt = 0; nt < 2; ++nt) bv[nt] = bias[c0 + wc * 32 + nt * 16 + l15];
#pragma unroll
    for (int mt = 0; mt < 4; ++mt)
#pragma unroll
        for (int reg = 0; reg < 4; ++reg) {
            int gr = r0 + wr * 64 + mt * 16 + quad * 4 + reg;
#pragma unroll
            for (int nt = 0; nt < 2; ++nt) {
                int gc = c0 + wc * 32 + nt * 16 + l15;
                out[(size_t)gr * Dc + gc] = acc[mt][nt][reg] + bv[nt];
            }
        }
}

// ---------------------------------------------------------------------------
extern "C" void kernel_launch(void* const* d_in, const int* in_sizes, int n_in,
                              void* d_out, int out_size, void* d_ws, size_t ws_size,
                              hipStream_t stream) {
    const float* x      = (const float*)d_in[0];
    const float* W_qkv  = (const float*)d_in[1];
    const float* b_qkv  = (const float*)d_in[2];
    const float* W_proj = (const float*)d_in[3];
    const float* b_proj = (const float*)d_in[4];
    float* out = (float*)d_out;

    char* ws = (char*)d_ws;
    size_t off = 0;
    auto take = [&](size_t bytes) -> char* {
        char* p = ws + off;
        off += (bytes + 255) & ~(size_t)255;
        return p;
    };
    unsigned int*   cnt = (unsigned int*)take(4096);   // cnt + 744 flags
    unsigned int*   flg = cnt + 64;                    // 256B offset
    unsigned short* WqT = (unsigned short*)take((size_t)Nqkv * Dc * 2);  // [2304][768]
    unsigned short* WpT = (unsigned short*)take((size_t)Dc * Dc * 2);    // [768][768]
    unsigned short* Qb  = (unsigned short*)take((size_t)BHc * Tc * DKc * 2);
    unsigned short* Kb  = (unsigned short*)take((size_t)BHc * Tc * DKc * 2);
    unsigned short* Vt  = (unsigned short*)take((size_t)BHc * Tc * DKc * 2);
    unsigned short* Xb  = (unsigned short*)take((size_t)Mc * Dc * 2);
    float*          Op  = (float*)take((size_t)NPAIR * 2 * 64 * 128 * 4);  // 47.7MB
    float*          Lp  = (float*)take((size_t)NPAIR * 2 * 128 * 4);
    unsigned short* An  = Xb;  // alias: Xb dead after qkv_gemm

    hipMemsetAsync(cnt, 0, 4096, stream);
    xconv_kernel<<<dim3((Mc * Dc) / (256 * 8)), dim3(256), 0, stream>>>(x, Xb);
    wtrans_kernel<<<dim3(Dc / 64, (Nqkv + Dc) / 64), dim3(256), 0, stream>>>(W_qkv, W_proj, WqT, WpT);
    qkv_gemm_kernel<<<dim3(Mc / 128, Nqkv / 128), dim3(256), 0, stream>>>(Xb, WqT, b_qkv, Qb, Kb, Vt);
    attn_kernel<<<dim3(NIT), dim3(256), 0, stream>>>(Qb, Kb, Vt, An, cnt, flg, Op, Lp);
    proj_gemm_kernel<<<dim3(Mc / 128, Dc / 64), dim3(256), 0, stream>>>(An, WpT, b_proj, out);
}

// Round 7
// 291.752 us; speedup vs baseline: 2.5962x; 2.5962x over previous
//
#include <hip/hip_runtime.h>
#include <hip/hip_bf16.h>
#include <cstdint>
#include <cstddef>

// ---------------------------------------------------------------------------
// CausalSelfAttention: x[2,4096,768] fp32, W_qkv[768,2304], b_qkv, W_proj[768,768], b_proj
// bf16 MFMA. All staging via __builtin_amdgcn_global_load_lds(16B) with
// XOR-swizzled source chunks. Attention: one (bh, 128-row qblock) per block;
// P stays in registers via mfma_16x16x16bf16_1k.
// R4: never hold staging loads in VGPRs across compute (spills).
// R6: LDS staging is mandatory for 4-wave-reused operands.
// R7: dbuf + counted vmcnt prefetch = NEUTRAL (TLP already hides it).
// R8: removing the mid-tile barrier = REGRESSION. Lockstep is right.
// R9: 128-key tiles = REGRESSION (VGPR 148, occupancy 16->11).
// R10: 64-row items = REGRESSION (staging per unit compute doubled).
// R11: VALU diet = NEUTRAL on attn; proj 128x64 + merged wtrans = -5us. BEST.
// R12: key-split + global merge = CATASTROPHE (WRITE 800MB: 4B atomic
//      stores amplify to full lines; merge round-trip serializes). Reverted.
// R13 (this round): all 768 attn items are co-resident (grid==items), so the
// atomic queue is pure overhead and the concurrent K/V working set is all
// 50MB -> L2 thrash (FETCH 124MB vs 50MB compulsory). Static XCD-aware map:
// bid&7 = XCD (round-robin dispatch), each XCD owns 3 bh x 32 qblocks ->
// 6.3MB K/V per XCD, each tile L2-resident for its 32 readers. Queue gone.
// ---------------------------------------------------------------------------

typedef __attribute__((ext_vector_type(8))) short bf16x8;   // 8 bf16 = 4 VGPRs
typedef __attribute__((ext_vector_type(4))) short bf16x4;   // 4 bf16 = 2 VGPRs
typedef __attribute__((ext_vector_type(4))) float f32x4;

#define MFMA16(a, b, c)   __builtin_amdgcn_mfma_f32_16x16x32_bf16((a), (b), (c), 0, 0, 0)
#define MFMA16K(a, b, c)  __builtin_amdgcn_mfma_f32_16x16x16bf16_1k((a), (b), (c), 0, 0, 0)

static constexpr int Bc = 2, Tc = 4096, Dc = 768, Hc = 12, DKc = 64;
static constexpr int BHc = Bc * Hc;      // 24
static constexpr int Mc = Bc * Tc;       // 8192
static constexpr int Nqkv = 3 * Dc;      // 2304
static constexpr int NQBLK = Tc / 128;   // 32 Q-blocks per bh
static constexpr unsigned int NITEMS = BHc * NQBLK;  // 768 blocks

__device__ __forceinline__ unsigned short f2bf(float f) {
    union { float f; unsigned int i; } c; c.f = f;
    unsigned int x = c.i;
    return (unsigned short)((x + 0x7fffu + ((x >> 16) & 1u)) >> 16); // RNE
}
__device__ __forceinline__ unsigned int pkbf(float a, float b) {
    __hip_bfloat162 h = __float22bfloat162_rn(make_float2(a, b));   // v_cvt_pk_bf16_f32
    union { __hip_bfloat162 h; unsigned int u; } c; c.h = h;
    return c.u;
}
// async global->LDS, 16B per lane; LDS dest = wave-uniform base + lane*16
__device__ __forceinline__ void glds16(const unsigned short* g, unsigned short* l) {
    __builtin_amdgcn_global_load_lds(
        (const __attribute__((address_space(1))) unsigned int*)g,
        (__attribute__((address_space(3))) unsigned int*)l, 16, 0, 0);
}

// ---------------------------------------------------------------------------
// x fp32 -> bf16, flat copy.
// ---------------------------------------------------------------------------
__global__ __launch_bounds__(256)
void xconv_kernel(const float* __restrict__ X, unsigned short* __restrict__ Xb) {
    size_t i = ((size_t)blockIdx.x * 256 + threadIdx.x) * 8;
    float4 a = *(const float4*)(X + i);
    float4 b = *(const float4*)(X + i + 4);
    uint4 o;
    o.x = pkbf(a.x, a.y); o.y = pkbf(a.z, a.w);
    o.z = pkbf(b.x, b.y); o.w = pkbf(b.z, b.w);
    *(uint4*)(Xb + i) = o;
}

// ---------------------------------------------------------------------------
// W [768][N] fp32 -> WT [N][768] bf16, both weight matrices in ONE launch.
// grid (12, 48): y<36 -> W_qkv (N=2304), else W_proj (N=768). 256 thr.
// ---------------------------------------------------------------------------
__global__ __launch_bounds__(256)
void wtrans_kernel(const float* __restrict__ Wq, const float* __restrict__ Wp,
                   unsigned short* __restrict__ WqT, unsigned short* __restrict__ WpT) {
    __shared__ __align__(16) unsigned short tile[64 * 72];
    const int k0 = blockIdx.x * 64;
    const int yb = blockIdx.y;
    const float* W;
    unsigned short* WT;
    int N, n0;
    if (yb < 36) { W = Wq; WT = WqT; N = Nqkv; n0 = yb * 64; }
    else         { W = Wp; WT = WpT; N = Dc;   n0 = (yb - 36) * 64; }
    const int tid = threadIdx.x;
#pragma unroll
    for (int it = 0; it < 4; ++it) {
        int s = tid + it * 256;
        int r = s >> 4, g = s & 15;
        float4 v = *(const float4*)(W + (size_t)(k0 + r) * N + n0 + g * 4);
        ushort4 u;
        u.x = f2bf(v.x); u.y = f2bf(v.y); u.z = f2bf(v.z); u.w = f2bf(v.w);
        *(ushort4*)(tile + r * 72 + g * 4) = u;
    }
    __syncthreads();
#pragma unroll
    for (int it = 0; it < 2; ++it) {
        int s = tid + it * 256;
        int n = s >> 3, g = s & 7;
        unsigned int p0 = (unsigned int)tile[(g * 8 + 0) * 72 + n] |
                          ((unsigned int)tile[(g * 8 + 1) * 72 + n] << 16);
        unsigned int p1 = (unsigned int)tile[(g * 8 + 2) * 72 + n] |
                          ((unsigned int)tile[(g * 8 + 3) * 72 + n] << 16);
        unsigned int p2 = (unsigned int)tile[(g * 8 + 4) * 72 + n] |
                          ((unsigned int)tile[(g * 8 + 5) * 72 + n] << 16);
        unsigned int p3 = (unsigned int)tile[(g * 8 + 6) * 72 + n] |
                          ((unsigned int)tile[(g * 8 + 7) * 72 + n] << 16);
        uint4 o; o.x = p0; o.y = p1; o.z = p2; o.w = p3;
        *(uint4*)(WT + (size_t)(n0 + n) * Dc + k0 + g * 8) = o;
    }
}

// ---------------------------------------------------------------------------
// QKV GEMM: Xb[8192][768] bf16 x WqT[2304][768] bf16 (+bias) -> Q/K [bh][t][dk],
// V transposed to Vt [bh][dk][t]. Q pre-scaled by 0.125*log2(e).
// BK=64, global_load_lds staging, XOR-swizzled chunks. grid (64,18).
// ---------------------------------------------------------------------------
__global__ __launch_bounds__(256)
void qkv_gemm_kernel(const unsigned short* __restrict__ Xb,
                     const unsigned short* __restrict__ WT,
                     const float* __restrict__ bias,
                     unsigned short* __restrict__ Qb, unsigned short* __restrict__ Kb,
                     unsigned short* __restrict__ Vt) {
    __shared__ __align__(16) unsigned short As[128 * 64];  // [row][64K], swizzled
    __shared__ __align__(16) unsigned short Bs[128 * 64];
    const int tid = threadIdx.x;
    const int wave = tid >> 6, lane = tid & 63;
    const int quad = lane >> 4, l15 = lane & 15;
    const int wr = wave >> 1, wc = wave & 1;
    const int r0 = blockIdx.x * 128, c0 = blockIdx.y * 128;
    const int sw = l15 & 7;   // fragment-read swizzle key (row&7 == l15&7)

    f32x4 acc[4][4];
#pragma unroll
    for (int i = 0; i < 4; ++i)
#pragma unroll
        for (int j = 0; j < 4; ++j) acc[i][j] = (f32x4){0.f, 0.f, 0.f, 0.f};

    for (int k0 = 0; k0 < Dc; k0 += 64) {
#pragma unroll
        for (int it = 0; it < 4; ++it) {      // stage 128x64 A and B tiles
            int idx = it * 256 + tid;
            int r = idx >> 3, c = idx & 7;
            int cg = c ^ (r & 7);             // LDS slot c holds global chunk cg
            glds16(Xb + (size_t)(r0 + r) * Dc + k0 + cg * 8, As + idx * 8);
            glds16(WT + (size_t)(c0 + r) * Dc + k0 + cg * 8, Bs + idx * 8);
        }
        __syncthreads();
#pragma unroll
        for (int f = 0; f < 2; ++f) {
            bf16x8 af[4], bfr[4];
#pragma unroll
            for (int mt = 0; mt < 4; ++mt)
                af[mt] = *(const bf16x8*)(As + (wr * 64 + mt * 16 + l15) * 64 +
                                          (((f * 4 + quad) ^ sw) * 8));
#pragma unroll
            for (int nt = 0; nt < 4; ++nt)
                bfr[nt] = *(const bf16x8*)(Bs + (wc * 64 + nt * 16 + l15) * 64 +
                                           (((f * 4 + quad) ^ sw) * 8));
#pragma unroll
            for (int mt = 0; mt < 4; ++mt)
#pragma unroll
                for (int nt = 0; nt < 4; ++nt)
                    acc[mt][nt] = MFMA16(af[mt], bfr[nt], acc[mt][nt]);
        }
        __syncthreads();
    }

    const int part = c0 / Dc;
    const int cbase = c0 - part * Dc;
    const float scale = (part == 0) ? 0.125f * 1.4426950408889634f : 1.0f;
    float bv[4];
#pragma unroll
    for (int nt = 0; nt < 4; ++nt) bv[nt] = bias[c0 + wc * 64 + nt * 16 + l15];

    if (part < 2) {
        unsigned short* dstbuf = (part == 0) ? Qb : Kb;
#pragma unroll
        for (int mt = 0; mt < 4; ++mt)
#pragma unroll
            for (int reg = 0; reg < 4; ++reg) {
                int gr = r0 + wr * 64 + mt * 16 + quad * 4 + reg;
                int b = gr >> 12, t = gr & 4095;
#pragma unroll
                for (int nt = 0; nt < 4; ++nt) {
                    int cc = cbase + wc * 64 + nt * 16 + l15;
                    int h = cc >> 6, dk = cc & 63;
                    float v = (acc[mt][nt][reg] + bv[nt]) * scale;
                    dstbuf[((size_t)(b * Hc + h) * Tc + t) * DKc + dk] = f2bf(v);
                }
            }
    } else {
        // V: write transposed [bh][dk][t]
#pragma unroll
        for (int mt = 0; mt < 4; ++mt)
#pragma unroll
            for (int reg = 0; reg < 4; ++reg) {
                int gr = r0 + wr * 64 + mt * 16 + quad * 4 + reg;
                int b = gr >> 12, t = gr & 4095;
#pragma unroll
                for (int nt = 0; nt < 4; ++nt) {
                    int cc = cbase + wc * 64 + nt * 16 + l15;
                    int h = cc >> 6, dk = cc & 63;
                    float v = acc[mt][nt][reg] + bv[nt];
                    Vt[((size_t)(b * Hc + h) * DKc + dk) * Tc + t] = f2bf(v);
                }
            }
    }
}

// ---------------------------------------------------------------------------
// Flash attention: 768 blocks, STATIC XCD-aware assignment (no queue):
//   xcd = bid & 7 (round-robin dispatch heuristic), j = bid >> 3 (0..95),
//   bh = xcd*3 + (j>>5)  (3 bh per XCD),  qb = j & 31.
// Each XCD's L2 then holds 3 bh x (K+V) = 6.3MB; every K/V tile is read by
// the 32 co-resident qblocks of its bh on the same XCD.
// Per 64-key tile: EXACT R0 lockstep (stage -> sync -> frags -> lgkm+barrier
// EARLY -> QK(czero) -> mask? -> exp2/pack -> lsum,PV via MFMA16K;
// lsum += MFMA16K(ones,P) = rowsum on the matrix pipe).
// ---------------------------------------------------------------------------
__global__ __launch_bounds__(256)
void attn_kernel(const unsigned short* __restrict__ Qb,
                 const unsigned short* __restrict__ Kb,
                 const unsigned short* __restrict__ Vt,
                 unsigned short* __restrict__ attn) {
    __shared__ __align__(16) unsigned short Ks[64 * 64];   // [key][dk] swizzled
    __shared__ __align__(16) unsigned short Vs[64 * 64];   // [dk][key] swizzled
    const int tid = threadIdx.x;
    const int wave = tid >> 6, lane = tid & 63;
    const int quad = lane >> 4, l15 = lane & 15;
    const int sw = l15 & 7;
    const f32x4 czero = (f32x4){0.f, 0.f, 0.f, 0.f};
    const bf16x4 ones = (bf16x4){(short)0x3F80, (short)0x3F80,
                                 (short)0x3F80, (short)0x3F80};  // bf16 1.0 x4

    const int bid = blockIdx.x;
    const int xcd = bid & 7, j = bid >> 3;
    const int bh = xcd * 3 + (j >> 5);     // 0..23
    const int qb = j & 31;                 // 0..31
    const int i0 = qb * 128;

    const unsigned short* Qp = Qb + (size_t)bh * Tc * DKc;
    const unsigned short* Kp = Kb + (size_t)bh * Tc * DKc;
    const unsigned short* Vp = Vt + (size_t)bh * DKc * Tc;

    // Q fragments for this wave's 32 rows (pre-scaled 0.125*log2e)
    bf16x8 qf[2][2];
#pragma unroll
    for (int qg = 0; qg < 2; ++qg)
#pragma unroll
        for (int f = 0; f < 2; ++f)
            qf[qg][f] = *(const bf16x8*)(Qp +
                (size_t)(i0 + wave * 32 + qg * 16 + l15) * DKc + f * 32 + quad * 8);

    f32x4 lsum[2] = {czero, czero};
    f32x4 o[2][4];
#pragma unroll
    for (int qg = 0; qg < 2; ++qg)
#pragma unroll
        for (int d = 0; d < 4; ++d) o[qg][d] = (f32x4){0.f, 0.f, 0.f, 0.f};

    const int jmax = (i0 >> 6) + 1;                    // tiles 0..jmax
    for (int jt = 0; jt <= jmax; ++jt) {
        const int j0 = jt * 64;
#pragma unroll
        for (int it = 0; it < 2; ++it) {               // async staging, swizzled
            int idx = it * 256 + tid;
            int r = idx >> 3, c = idx & 7;
            int cg = c ^ (r & 7);
            glds16(Kp + (size_t)(j0 + r) * DKc + cg * 8, Ks + idx * 8);
            glds16(Vp + (size_t)r * Tc + j0 + cg * 8, Vs + idx * 8);
        }
        __syncthreads();

        // fragments -> regs; then barrier EARLY so next staging can begin
        bf16x8 kf[2][4];
        bf16x4 vf[4][4];
#pragma unroll
        for (int f = 0; f < 2; ++f)
#pragma unroll
            for (int mt = 0; mt < 4; ++mt)
                kf[f][mt] = *(const bf16x8*)(Ks + (mt * 16 + l15) * 64 +
                                             (((f * 4 + quad) ^ sw) * 8));
#pragma unroll
        for (int d = 0; d < 4; ++d)
#pragma unroll
            for (int mt = 0; mt < 4; ++mt) {
                int g8 = mt * 4 + quad;
                vf[d][mt] = *(const bf16x4*)(Vs + (d * 16 + l15) * 64 +
                                             (((g8 >> 1) ^ sw) * 8) + (g8 & 1) * 4);
            }
        asm volatile("s_waitcnt lgkmcnt(0)" ::: "memory");
        __builtin_amdgcn_s_barrier();

        // S^T: C-layout key=16mt+quad*4+reg, q=l15; czero folds the init
        f32x4 sc[2][4];
#pragma unroll
        for (int mt = 0; mt < 4; ++mt) {
            sc[0][mt] = MFMA16(kf[0][mt], qf[0][0], czero);
            sc[1][mt] = MFMA16(kf[0][mt], qf[1][0], czero);
        }
#pragma unroll
        for (int mt = 0; mt < 4; ++mt) {
            sc[0][mt] = MFMA16(kf[1][mt], qf[0][1], sc[0][mt]);
            sc[1][mt] = MFMA16(kf[1][mt], qf[1][1], sc[1][mt]);
        }

        const int rel = j0 - i0;
        if (jt >= jmax - 1) {                          // diagonal region
#pragma unroll
            for (int qg = 0; qg < 2; ++qg) {
                int qrow = wave * 32 + qg * 16 + l15;
#pragma unroll
                for (int mt = 0; mt < 4; ++mt)
#pragma unroll
                    for (int reg = 0; reg < 4; ++reg)
                        if (rel + mt * 16 + quad * 4 + reg > qrow)
                            sc[qg][mt][reg] = -1e30f;
            }
        }

        // exp2 + pack P^T (B-operand, in-register)
        union { uint2 u; bf16x4 v; } pb[2][4];
#pragma unroll
        for (int qg = 0; qg < 2; ++qg)
#pragma unroll
            for (int mt = 0; mt < 4; ++mt) {
#pragma unroll
                for (int reg = 0; reg < 4; ++reg)
                    sc[qg][mt][reg] = __builtin_amdgcn_exp2f(sc[qg][mt][reg]);
                pb[qg][mt].u.x = pkbf(sc[qg][mt][0], sc[qg][mt][1]);
                pb[qg][mt].u.y = pkbf(sc[qg][mt][2], sc[qg][mt][3]);
            }

        // lsum += colsum(P^T) (= rowsum for q=l15); O^T += V^T P^T
#pragma unroll
        for (int mt = 0; mt < 4; ++mt) {
            lsum[0] = MFMA16K(ones, pb[0][mt].v, lsum[0]);
            lsum[1] = MFMA16K(ones, pb[1][mt].v, lsum[1]);
#pragma unroll
            for (int d = 0; d < 4; ++d) {
                o[0][d] = MFMA16K(vf[d][mt], pb[0][mt].v, o[0][d]);
                o[1][d] = MFMA16K(vf[d][mt], pb[1][mt].v, o[1][d]);
            }
        }
    }

    // normalize + store: lane owns q = i0+wave*32+qg*16+l15 for all o;
    // lsum regs are identical (every C row = the same column sum)
    const int b = bh / Hc, h = bh % Hc;
#pragma unroll
    for (int qg = 0; qg < 2; ++qg) {
        float li = 1.0f / lsum[qg][0];
        int t = i0 + wave * 32 + qg * 16 + l15;
        unsigned short* dst = attn + (size_t)(b * Tc + t) * Dc + h * 64;
#pragma unroll
        for (int d = 0; d < 4; ++d) {
            uint2 u;
            u.x = pkbf(o[qg][d][0] * li, o[qg][d][1] * li);
            u.y = pkbf(o[qg][d][2] * li, o[qg][d][3] * li);
            *(uint2*)(dst + d * 16 + quad * 4) = u;
        }
    }
}

// ---------------------------------------------------------------------------
// Proj GEMM: A[8192][768] bf16 x WpT[768][768] bf16 (+bias) -> out fp32
// 128x64 tiles, BK=64: grid (64,12) = 768 blocks = 3/CU exact (no tail).
// ---------------------------------------------------------------------------
__global__ __launch_bounds__(256)
void proj_gemm_kernel(const unsigned short* __restrict__ A,
                      const unsigned short* __restrict__ WT,
                      const float* __restrict__ bias, float* __restrict__ out) {
    __shared__ __align__(16) unsigned short As[128 * 64];
    __shared__ __align__(16) unsigned short Bs[64 * 64];
    const int tid = threadIdx.x;
    const int wave = tid >> 6, lane = tid & 63;
    const int quad = lane >> 4, l15 = lane & 15;
    const int wr = wave >> 1, wc = wave & 1;
    const int r0 = blockIdx.x * 128, c0 = blockIdx.y * 64;
    const int sw = l15 & 7;

    f32x4 acc[4][2];
#pragma unroll
    for (int i = 0; i < 4; ++i)
#pragma unroll
        for (int j = 0; j < 2; ++j) acc[i][j] = (f32x4){0.f, 0.f, 0.f, 0.f};

    for (int k0 = 0; k0 < Dc; k0 += 64) {
#pragma unroll
        for (int it = 0; it < 4; ++it) {      // A: 128 rows x 8 chunks
            int idx = it * 256 + tid;
            int r = idx >> 3, c = idx & 7;
            glds16(A + (size_t)(r0 + r) * Dc + k0 + ((c ^ (r & 7)) * 8), As + idx * 8);
        }
#pragma unroll
        for (int it = 0; it < 2; ++it) {      // B: 64 rows x 8 chunks
            int idx = it * 256 + tid;
            int r = idx >> 3, c = idx & 7;
            glds16(WT + (size_t)(c0 + r) * Dc + k0 + ((c ^ (r & 7)) * 8), Bs + idx * 8);
        }
        __syncthreads();
#pragma unroll
        for (int f = 0; f < 2; ++f) {
            bf16x8 af[4], bfr[2];
#pragma unroll
            for (int mt = 0; mt < 4; ++mt)
                af[mt] = *(const bf16x8*)(As + (wr * 64 + mt * 16 + l15) * 64 +
                                          (((f * 4 + quad) ^ sw) * 8));
#pragma unroll
            for (int nt = 0; nt < 2; ++nt)
                bfr[nt] = *(const bf16x8*)(Bs + (wc * 32 + nt * 16 + l15) * 64 +
                                           (((f * 4 + quad) ^ sw) * 8));
#pragma unroll
            for (int mt = 0; mt < 4; ++mt)
#pragma unroll
                for (int nt = 0; nt < 2; ++nt)
                    acc[mt][nt] = MFMA16(af[mt], bfr[nt], acc[mt][nt]);
        }
        __syncthreads();
    }

    float bv[2];
#pragma unroll
    for (int nt = 0; nt < 2; ++nt) bv[nt] = bias[c0 + wc * 32 + nt * 16 + l15];
#pragma unroll
    for (int mt = 0; mt < 4; ++mt)
#pragma unroll
        for (int reg = 0; reg < 4; ++reg) {
            int gr = r0 + wr * 64 + mt * 16 + quad * 4 + reg;
#pragma unroll
            for (int nt = 0; nt < 2; ++nt) {
                int gc = c0 + wc * 32 + nt * 16 + l15;
                out[(size_t)gr * Dc + gc] = acc[mt][nt][reg] + bv[nt];
            }
        }
}

// ---------------------------------------------------------------------------
extern "C" void kernel_launch(void* const* d_in, const int* in_sizes, int n_in,
                              void* d_out, int out_size, void* d_ws, size_t ws_size,
                              hipStream_t stream) {
    const float* x      = (const float*)d_in[0];
    const float* W_qkv  = (const float*)d_in[1];
    const float* b_qkv  = (const float*)d_in[2];
    const float* W_proj = (const float*)d_in[3];
    const float* b_proj = (const float*)d_in[4];
    float* out = (float*)d_out;

    char* ws = (char*)d_ws;
    size_t off = 0;
    auto take = [&](size_t bytes) -> char* {
        char* p = ws + off;
        off += (bytes + 255) & ~(size_t)255;
        return p;
    };
    unsigned short* WqT = (unsigned short*)take((size_t)Nqkv * Dc * 2);  // [2304][768]
    unsigned short* WpT = (unsigned short*)take((size_t)Dc * Dc * 2);    // [768][768]
    unsigned short* Qb  = (unsigned short*)take((size_t)BHc * Tc * DKc * 2);
    unsigned short* Kb  = (unsigned short*)take((size_t)BHc * Tc * DKc * 2);
    unsigned short* Vt  = (unsigned short*)take((size_t)BHc * Tc * DKc * 2);
    unsigned short* Xb  = (unsigned short*)take((size_t)Mc * Dc * 2);
    unsigned short* An  = Xb;  // alias: Xb dead after qkv_gemm

    xconv_kernel<<<dim3((Mc * Dc) / (256 * 8)), dim3(256), 0, stream>>>(x, Xb);
    wtrans_kernel<<<dim3(Dc / 64, (Nqkv + Dc) / 64), dim3(256), 0, stream>>>(W_qkv, W_proj, WqT, WpT);
    qkv_gemm_kernel<<<dim3(Mc / 128, Nqkv / 128), dim3(256), 0, stream>>>(Xb, WqT, b_qkv, Qb, Kb, Vt);
    attn_kernel<<<dim3(NITEMS), dim3(256), 0, stream>>>(Qb, Kb, Vt, An);
    proj_gemm_kernel<<<dim3(Mc / 128, Dc / 64), dim3(256), 0, stream>>>(An, WpT, b_proj, out);
}

// Round 8
// 250.761 us; speedup vs baseline: 3.0206x; 1.1635x over previous
//
#include <hip/hip_runtime.h>
#include <hip/hip_bf16.h>
#include <cstdint>
#include <cstddef>

// ---------------------------------------------------------------------------
// CausalSelfAttention: x[2,4096,768] fp32, W_qkv[768,2304], b_qkv, W_proj[768,768], b_proj
// bf16 MFMA. All staging via __builtin_amdgcn_global_load_lds(16B) with
// XOR-swizzled source chunks. Attention: one (bh, 128-row qblock) per block;
// P stays in registers via mfma_16x16x16bf16_1k.
// R4: never hold staging loads in VGPRs across compute (spills).
// R6: LDS staging is mandatory for 4-wave-reused operands.
// R7: dbuf + counted vmcnt prefetch = NEUTRAL (TLP already hides it).
// R8: removing the mid-tile barrier = REGRESSION. Lockstep is right.
// R9: 128-key tiles = REGRESSION (VGPR 148, occupancy 16->11).
// R10: 64-row items = REGRESSION (staging per unit compute doubled).
// R11: VALU diet = NEUTRAL on attn; proj 128x64 + merged wtrans = -5us.
// R12: key-split + global merge = CATASTROPHE (4B stores amplify to lines).
// R13: static XCD map: FETCH 124->18.5MB (locality theory CONFIRMED, bid&7
//      == XCD) but dur 126->151: same-qb blocks stacked per CU = 2x imbalance.
// R14 (this round): per-XCD QUEUES = R13's locality + R11's balance.
// XCD x (bid&7) owns bh {3x..3x+2}, 96 items longest-first; blocks claim
// from their own counter (race order decorrelates qb from CU); work-stealing
// over the other 7 counters guarantees coverage regardless of dispatch
// policy (unique atomicAdd indices; exit only when all 8 exhausted).
// ---------------------------------------------------------------------------

typedef __attribute__((ext_vector_type(8))) short bf16x8;   // 8 bf16 = 4 VGPRs
typedef __attribute__((ext_vector_type(4))) short bf16x4;   // 4 bf16 = 2 VGPRs
typedef __attribute__((ext_vector_type(4))) float f32x4;

#define MFMA16(a, b, c)   __builtin_amdgcn_mfma_f32_16x16x32_bf16((a), (b), (c), 0, 0, 0)
#define MFMA16K(a, b, c)  __builtin_amdgcn_mfma_f32_16x16x16bf16_1k((a), (b), (c), 0, 0, 0)

static constexpr int Bc = 2, Tc = 4096, Dc = 768, Hc = 12, DKc = 64;
static constexpr int BHc = Bc * Hc;      // 24
static constexpr int Mc = Bc * Tc;       // 8192
static constexpr int Nqkv = 3 * Dc;      // 2304
static constexpr int NQBLK = Tc / 128;   // 32 Q-blocks per bh
static constexpr unsigned int NITEMS = BHc * NQBLK;  // 768 blocks
static constexpr unsigned int PERX = 96;             // items per XCD partition

__device__ __forceinline__ unsigned short f2bf(float f) {
    union { float f; unsigned int i; } c; c.f = f;
    unsigned int x = c.i;
    return (unsigned short)((x + 0x7fffu + ((x >> 16) & 1u)) >> 16); // RNE
}
__device__ __forceinline__ unsigned int pkbf(float a, float b) {
    __hip_bfloat162 h = __float22bfloat162_rn(make_float2(a, b));   // v_cvt_pk_bf16_f32
    union { __hip_bfloat162 h; unsigned int u; } c; c.h = h;
    return c.u;
}
// async global->LDS, 16B per lane; LDS dest = wave-uniform base + lane*16
__device__ __forceinline__ void glds16(const unsigned short* g, unsigned short* l) {
    __builtin_amdgcn_global_load_lds(
        (const __attribute__((address_space(1))) unsigned int*)g,
        (__attribute__((address_space(3))) unsigned int*)l, 16, 0, 0);
}

// ---------------------------------------------------------------------------
// x fp32 -> bf16, flat copy.
// ---------------------------------------------------------------------------
__global__ __launch_bounds__(256)
void xconv_kernel(const float* __restrict__ X, unsigned short* __restrict__ Xb) {
    size_t i = ((size_t)blockIdx.x * 256 + threadIdx.x) * 8;
    float4 a = *(const float4*)(X + i);
    float4 b = *(const float4*)(X + i + 4);
    uint4 o;
    o.x = pkbf(a.x, a.y); o.y = pkbf(a.z, a.w);
    o.z = pkbf(b.x, b.y); o.w = pkbf(b.z, b.w);
    *(uint4*)(Xb + i) = o;
}

// ---------------------------------------------------------------------------
// W [768][N] fp32 -> WT [N][768] bf16, both weight matrices in ONE launch.
// grid (12, 48): y<36 -> W_qkv (N=2304), else W_proj (N=768). 256 thr.
// ---------------------------------------------------------------------------
__global__ __launch_bounds__(256)
void wtrans_kernel(const float* __restrict__ Wq, const float* __restrict__ Wp,
                   unsigned short* __restrict__ WqT, unsigned short* __restrict__ WpT) {
    __shared__ __align__(16) unsigned short tile[64 * 72];
    const int k0 = blockIdx.x * 64;
    const int yb = blockIdx.y;
    const float* W;
    unsigned short* WT;
    int N, n0;
    if (yb < 36) { W = Wq; WT = WqT; N = Nqkv; n0 = yb * 64; }
    else         { W = Wp; WT = WpT; N = Dc;   n0 = (yb - 36) * 64; }
    const int tid = threadIdx.x;
#pragma unroll
    for (int it = 0; it < 4; ++it) {
        int s = tid + it * 256;
        int r = s >> 4, g = s & 15;
        float4 v = *(const float4*)(W + (size_t)(k0 + r) * N + n0 + g * 4);
        ushort4 u;
        u.x = f2bf(v.x); u.y = f2bf(v.y); u.z = f2bf(v.z); u.w = f2bf(v.w);
        *(ushort4*)(tile + r * 72 + g * 4) = u;
    }
    __syncthreads();
#pragma unroll
    for (int it = 0; it < 2; ++it) {
        int s = tid + it * 256;
        int n = s >> 3, g = s & 7;
        unsigned int p0 = (unsigned int)tile[(g * 8 + 0) * 72 + n] |
                          ((unsigned int)tile[(g * 8 + 1) * 72 + n] << 16);
        unsigned int p1 = (unsigned int)tile[(g * 8 + 2) * 72 + n] |
                          ((unsigned int)tile[(g * 8 + 3) * 72 + n] << 16);
        unsigned int p2 = (unsigned int)tile[(g * 8 + 4) * 72 + n] |
                          ((unsigned int)tile[(g * 8 + 5) * 72 + n] << 16);
        unsigned int p3 = (unsigned int)tile[(g * 8 + 6) * 72 + n] |
                          ((unsigned int)tile[(g * 8 + 7) * 72 + n] << 16);
        uint4 o; o.x = p0; o.y = p1; o.z = p2; o.w = p3;
        *(uint4*)(WT + (size_t)(n0 + n) * Dc + k0 + g * 8) = o;
    }
}

// ---------------------------------------------------------------------------
// QKV GEMM: Xb[8192][768] bf16 x WqT[2304][768] bf16 (+bias) -> Q/K [bh][t][dk],
// V transposed to Vt [bh][dk][t]. Q pre-scaled by 0.125*log2(e).
// BK=64, global_load_lds staging, XOR-swizzled chunks. grid (64,18).
// ---------------------------------------------------------------------------
__global__ __launch_bounds__(256)
void qkv_gemm_kernel(const unsigned short* __restrict__ Xb,
                     const unsigned short* __restrict__ WT,
                     const float* __restrict__ bias,
                     unsigned short* __restrict__ Qb, unsigned short* __restrict__ Kb,
                     unsigned short* __restrict__ Vt) {
    __shared__ __align__(16) unsigned short As[128 * 64];  // [row][64K], swizzled
    __shared__ __align__(16) unsigned short Bs[128 * 64];
    const int tid = threadIdx.x;
    const int wave = tid >> 6, lane = tid & 63;
    const int quad = lane >> 4, l15 = lane & 15;
    const int wr = wave >> 1, wc = wave & 1;
    const int r0 = blockIdx.x * 128, c0 = blockIdx.y * 128;
    const int sw = l15 & 7;   // fragment-read swizzle key (row&7 == l15&7)

    f32x4 acc[4][4];
#pragma unroll
    for (int i = 0; i < 4; ++i)
#pragma unroll
        for (int j = 0; j < 4; ++j) acc[i][j] = (f32x4){0.f, 0.f, 0.f, 0.f};

    for (int k0 = 0; k0 < Dc; k0 += 64) {
#pragma unroll
        for (int it = 0; it < 4; ++it) {      // stage 128x64 A and B tiles
            int idx = it * 256 + tid;
            int r = idx >> 3, c = idx & 7;
            int cg = c ^ (r & 7);             // LDS slot c holds global chunk cg
            glds16(Xb + (size_t)(r0 + r) * Dc + k0 + cg * 8, As + idx * 8);
            glds16(WT + (size_t)(c0 + r) * Dc + k0 + cg * 8, Bs + idx * 8);
        }
        __syncthreads();
#pragma unroll
        for (int f = 0; f < 2; ++f) {
            bf16x8 af[4], bfr[4];
#pragma unroll
            for (int mt = 0; mt < 4; ++mt)
                af[mt] = *(const bf16x8*)(As + (wr * 64 + mt * 16 + l15) * 64 +
                                          (((f * 4 + quad) ^ sw) * 8));
#pragma unroll
            for (int nt = 0; nt < 4; ++nt)
                bfr[nt] = *(const bf16x8*)(Bs + (wc * 64 + nt * 16 + l15) * 64 +
                                           (((f * 4 + quad) ^ sw) * 8));
#pragma unroll
            for (int mt = 0; mt < 4; ++mt)
#pragma unroll
                for (int nt = 0; nt < 4; ++nt)
                    acc[mt][nt] = MFMA16(af[mt], bfr[nt], acc[mt][nt]);
        }
        __syncthreads();
    }

    const int part = c0 / Dc;
    const int cbase = c0 - part * Dc;
    const float scale = (part == 0) ? 0.125f * 1.4426950408889634f : 1.0f;
    float bv[4];
#pragma unroll
    for (int nt = 0; nt < 4; ++nt) bv[nt] = bias[c0 + wc * 64 + nt * 16 + l15];

    if (part < 2) {
        unsigned short* dstbuf = (part == 0) ? Qb : Kb;
#pragma unroll
        for (int mt = 0; mt < 4; ++mt)
#pragma unroll
            for (int reg = 0; reg < 4; ++reg) {
                int gr = r0 + wr * 64 + mt * 16 + quad * 4 + reg;
                int b = gr >> 12, t = gr & 4095;
#pragma unroll
                for (int nt = 0; nt < 4; ++nt) {
                    int cc = cbase + wc * 64 + nt * 16 + l15;
                    int h = cc >> 6, dk = cc & 63;
                    float v = (acc[mt][nt][reg] + bv[nt]) * scale;
                    dstbuf[((size_t)(b * Hc + h) * Tc + t) * DKc + dk] = f2bf(v);
                }
            }
    } else {
        // V: write transposed [bh][dk][t]
#pragma unroll
        for (int mt = 0; mt < 4; ++mt)
#pragma unroll
            for (int reg = 0; reg < 4; ++reg) {
                int gr = r0 + wr * 64 + mt * 16 + quad * 4 + reg;
                int b = gr >> 12, t = gr & 4095;
#pragma unroll
                for (int nt = 0; nt < 4; ++nt) {
                    int cc = cbase + wc * 64 + nt * 16 + l15;
                    int h = cc >> 6, dk = cc & 63;
                    float v = acc[mt][nt][reg] + bv[nt];
                    Vt[((size_t)(b * Hc + h) * DKc + dk) * Tc + t] = f2bf(v);
                }
            }
    }
}

// ---------------------------------------------------------------------------
// Flash attention: 768 blocks, per-XCD queues + work stealing.
// XCD x = bid&7 (validated R13: FETCH 124->18.5MB) owns 96 items covering
// bh {3x..3x+2} x 32 qblocks, sorted longest-first (g=0.. -> qb=31..).
// tid0 claims: try own counter, then the other 7 (unique indices => each
// item claimed exactly once; exit only when all 8 exhausted => correct for
// ANY dispatch policy). Race-order claims decorrelate qb from CU (balance).
// Per 64-key tile: R0 lockstep (stage -> sync -> frags -> lgkm+barrier
// EARLY -> QK(czero) -> mask? -> exp2/pack -> lsum,PV via MFMA16K;
// lsum += MFMA16K(ones,P) = rowsum on the matrix pipe).
// ---------------------------------------------------------------------------
__global__ __launch_bounds__(256)
void attn_kernel(const unsigned short* __restrict__ Qb,
                 const unsigned short* __restrict__ Kb,
                 const unsigned short* __restrict__ Vt,
                 unsigned short* __restrict__ attn,
                 unsigned int* __restrict__ counters) {
    __shared__ __align__(16) unsigned short Ks[64 * 64];   // [key][dk] swizzled
    __shared__ __align__(16) unsigned short Vs[64 * 64];   // [dk][key] swizzled
    __shared__ unsigned int s_w;
    const int tid = threadIdx.x;
    const int wave = tid >> 6, lane = tid & 63;
    const int quad = lane >> 4, l15 = lane & 15;
    const int sw = l15 & 7;
    const f32x4 czero = (f32x4){0.f, 0.f, 0.f, 0.f};
    const bf16x4 ones = (bf16x4){(short)0x3F80, (short)0x3F80,
                                 (short)0x3F80, (short)0x3F80};  // bf16 1.0 x4
    const int myx = (int)(blockIdx.x & 7);

    for (;;) {
        if (tid == 0) {
            unsigned int got = 0xFFFFFFFFu;
#pragma unroll
            for (int p = 0; p < 8; ++p) {                  // own queue, then steal
                int q = (myx + p) & 7;
                unsigned int idx = atomicAdd(&counters[q * 32], 1u);
                if (idx < PERX) { got = (unsigned int)q * PERX + idx; break; }
            }
            s_w = got;
        }
        __syncthreads();
        const unsigned int w = s_w;
        if (w == 0xFFFFFFFFu) break;                       // all queues exhausted
        const int xg = (int)(w / PERX);                    // owning partition
        const int g  = (int)(w % PERX);
        const int qb = 31 - g / 3;                         // longest first
        const int bh = xg * 3 + (g % 3);
        const int i0 = qb * 128;

        const unsigned short* Qp = Qb + (size_t)bh * Tc * DKc;
        const unsigned short* Kp = Kb + (size_t)bh * Tc * DKc;
        const unsigned short* Vp = Vt + (size_t)bh * DKc * Tc;

        // Q fragments for this wave's 32 rows (pre-scaled 0.125*log2e)
        bf16x8 qf[2][2];
#pragma unroll
        for (int qg = 0; qg < 2; ++qg)
#pragma unroll
            for (int f = 0; f < 2; ++f)
                qf[qg][f] = *(const bf16x8*)(Qp +
                    (size_t)(i0 + wave * 32 + qg * 16 + l15) * DKc + f * 32 + quad * 8);

        f32x4 lsum[2] = {czero, czero};
        f32x4 o[2][4];
#pragma unroll
        for (int qg = 0; qg < 2; ++qg)
#pragma unroll
            for (int d = 0; d < 4; ++d) o[qg][d] = (f32x4){0.f, 0.f, 0.f, 0.f};

        const int jmax = (i0 >> 6) + 1;                    // tiles 0..jmax
        for (int jt = 0; jt <= jmax; ++jt) {
            const int j0 = jt * 64;
#pragma unroll
            for (int it = 0; it < 2; ++it) {               // async staging, swizzled
                int idx = it * 256 + tid;
                int r = idx >> 3, c = idx & 7;
                int cg = c ^ (r & 7);
                glds16(Kp + (size_t)(j0 + r) * DKc + cg * 8, Ks + idx * 8);
                glds16(Vp + (size_t)r * Tc + j0 + cg * 8, Vs + idx * 8);
            }
            __syncthreads();

            // fragments -> regs; then barrier EARLY so next staging can begin
            bf16x8 kf[2][4];
            bf16x4 vf[4][4];
#pragma unroll
            for (int f = 0; f < 2; ++f)
#pragma unroll
                for (int mt = 0; mt < 4; ++mt)
                    kf[f][mt] = *(const bf16x8*)(Ks + (mt * 16 + l15) * 64 +
                                                 (((f * 4 + quad) ^ sw) * 8));
#pragma unroll
            for (int d = 0; d < 4; ++d)
#pragma unroll
                for (int mt = 0; mt < 4; ++mt) {
                    int g8 = mt * 4 + quad;
                    vf[d][mt] = *(const bf16x4*)(Vs + (d * 16 + l15) * 64 +
                                                 (((g8 >> 1) ^ sw) * 8) + (g8 & 1) * 4);
                }
            asm volatile("s_waitcnt lgkmcnt(0)" ::: "memory");
            __builtin_amdgcn_s_barrier();

            // S^T: C-layout key=16mt+quad*4+reg, q=l15; czero folds the init
            f32x4 sc[2][4];
#pragma unroll
            for (int mt = 0; mt < 4; ++mt) {
                sc[0][mt] = MFMA16(kf[0][mt], qf[0][0], czero);
                sc[1][mt] = MFMA16(kf[0][mt], qf[1][0], czero);
            }
#pragma unroll
            for (int mt = 0; mt < 4; ++mt) {
                sc[0][mt] = MFMA16(kf[1][mt], qf[0][1], sc[0][mt]);
                sc[1][mt] = MFMA16(kf[1][mt], qf[1][1], sc[1][mt]);
            }

            const int rel = j0 - i0;
            if (jt >= jmax - 1) {                          // diagonal region
#pragma unroll
                for (int qg = 0; qg < 2; ++qg) {
                    int qrow = wave * 32 + qg * 16 + l15;
#pragma unroll
                    for (int mt = 0; mt < 4; ++mt)
#pragma unroll
                        for (int reg = 0; reg < 4; ++reg)
                            if (rel + mt * 16 + quad * 4 + reg > qrow)
                                sc[qg][mt][reg] = -1e30f;
                }
            }

            // exp2 + pack P^T (B-operand, in-register)
            union { uint2 u; bf16x4 v; } pb[2][4];
#pragma unroll
            for (int qg = 0; qg < 2; ++qg)
#pragma unroll
                for (int mt = 0; mt < 4; ++mt) {
#pragma unroll
                    for (int reg = 0; reg < 4; ++reg)
                        sc[qg][mt][reg] = __builtin_amdgcn_exp2f(sc[qg][mt][reg]);
                    pb[qg][mt].u.x = pkbf(sc[qg][mt][0], sc[qg][mt][1]);
                    pb[qg][mt].u.y = pkbf(sc[qg][mt][2], sc[qg][mt][3]);
                }

            // lsum += colsum(P^T) (= rowsum for q=l15); O^T += V^T P^T
#pragma unroll
            for (int mt = 0; mt < 4; ++mt) {
                lsum[0] = MFMA16K(ones, pb[0][mt].v, lsum[0]);
                lsum[1] = MFMA16K(ones, pb[1][mt].v, lsum[1]);
#pragma unroll
                for (int d = 0; d < 4; ++d) {
                    o[0][d] = MFMA16K(vf[d][mt], pb[0][mt].v, o[0][d]);
                    o[1][d] = MFMA16K(vf[d][mt], pb[1][mt].v, o[1][d]);
                }
            }
        }

        // normalize + store: lane owns q = i0+wave*32+qg*16+l15 for all o;
        // lsum regs are identical (every C row = the same column sum)
        const int b = bh / Hc, h = bh % Hc;
#pragma unroll
        for (int qg = 0; qg < 2; ++qg) {
            float li = 1.0f / lsum[qg][0];
            int t = i0 + wave * 32 + qg * 16 + l15;
            unsigned short* dst = attn + (size_t)(b * Tc + t) * Dc + h * 64;
#pragma unroll
            for (int d = 0; d < 4; ++d) {
                uint2 u;
                u.x = pkbf(o[qg][d][0] * li, o[qg][d][1] * li);
                u.y = pkbf(o[qg][d][2] * li, o[qg][d][3] * li);
                *(uint2*)(dst + d * 16 + quad * 4) = u;
            }
        }
    }
}

// ---------------------------------------------------------------------------
// Proj GEMM: A[8192][768] bf16 x WpT[768][768] bf16 (+bias) -> out fp32
// 128x64 tiles, BK=64: grid (64,12) = 768 blocks = 3/CU exact (no tail).
// ---------------------------------------------------------------------------
__global__ __launch_bounds__(256)
void proj_gemm_kernel(const unsigned short* __restrict__ A,
                      const unsigned short* __restrict__ WT,
                      const float* __restrict__ bias, float* __restrict__ out) {
    __shared__ __align__(16) unsigned short As[128 * 64];
    __shared__ __align__(16) unsigned short Bs[64 * 64];
    const int tid = threadIdx.x;
    const int wave = tid >> 6, lane = tid & 63;
    const int quad = lane >> 4, l15 = lane & 15;
    const int wr = wave >> 1, wc = wave & 1;
    const int r0 = blockIdx.x * 128, c0 = blockIdx.y * 64;
    const int sw = l15 & 7;

    f32x4 acc[4][2];
#pragma unroll
    for (int i = 0; i < 4; ++i)
#pragma unroll
        for (int j = 0; j < 2; ++j) acc[i][j] = (f32x4){0.f, 0.f, 0.f, 0.f};

    for (int k0 = 0; k0 < Dc; k0 += 64) {
#pragma unroll
        for (int it = 0; it < 4; ++it) {      // A: 128 rows x 8 chunks
            int idx = it * 256 + tid;
            int r = idx >> 3, c = idx & 7;
            glds16(A + (size_t)(r0 + r) * Dc + k0 + ((c ^ (r & 7)) * 8), As + idx * 8);
        }
#pragma unroll
        for (int it = 0; it < 2; ++it) {      // B: 64 rows x 8 chunks
            int idx = it * 256 + tid;
            int r = idx >> 3, c = idx & 7;
            glds16(WT + (size_t)(c0 + r) * Dc + k0 + ((c ^ (r & 7)) * 8), Bs + idx * 8);
        }
        __syncthreads();
#pragma unroll
        for (int f = 0; f < 2; ++f) {
            bf16x8 af[4], bfr[2];
#pragma unroll
            for (int mt = 0; mt < 4; ++mt)
                af[mt] = *(const bf16x8*)(As + (wr * 64 + mt * 16 + l15) * 64 +
                                          (((f * 4 + quad) ^ sw) * 8));
#pragma unroll
            for (int nt = 0; nt < 2; ++nt)
                bfr[nt] = *(const bf16x8*)(Bs + (wc * 32 + nt * 16 + l15) * 64 +
                                           (((f * 4 + quad) ^ sw) * 8));
#pragma unroll
            for (int mt = 0; mt < 4; ++mt)
#pragma unroll
                for (int nt = 0; nt < 2; ++nt)
                    acc[mt][nt] = MFMA16(af[mt], bfr[nt], acc[mt][nt]);
        }
        __syncthreads();
    }

    float bv[2];
#pragma unroll
    for (int nt = 0; nt < 2; ++nt) bv[nt] = bias[c0 + wc * 32 + nt * 16 + l15];
#pragma unroll
    for (int mt = 0; mt < 4; ++mt)
#pragma unroll
        for (int reg = 0; reg < 4; ++reg) {
            int gr = r0 + wr * 64 + mt * 16 + quad * 4 + reg;
#pragma unroll
            for (int nt = 0; nt < 2; ++nt) {
                int gc = c0 + wc * 32 + nt * 16 + l15;
                out[(size_t)gr * Dc + gc] = acc[mt][nt][reg] + bv[nt];
            }
        }
}

// ---------------------------------------------------------------------------
extern "C" void kernel_launch(void* const* d_in, const int* in_sizes, int n_in,
                              void* d_out, int out_size, void* d_ws, size_t ws_size,
                              hipStream_t stream) {
    const float* x      = (const float*)d_in[0];
    const float* W_qkv  = (const float*)d_in[1];
    const float* b_qkv  = (const float*)d_in[2];
    const float* W_proj = (const float*)d_in[3];
    const float* b_proj = (const float*)d_in[4];
    float* out = (float*)d_out;

    char* ws = (char*)d_ws;
    size_t off = 0;
    auto take = [&](size_t bytes) -> char* {
        char* p = ws + off;
        off += (bytes + 255) & ~(size_t)255;
        return p;
    };
    unsigned int*   cnt = (unsigned int*)take(4096);   // 8 counters, 128B apart
    unsigned short* WqT = (unsigned short*)take((size_t)Nqkv * Dc * 2);  // [2304][768]
    unsigned short* WpT = (unsigned short*)take((size_t)Dc * Dc * 2);    // [768][768]
    unsigned short* Qb  = (unsigned short*)take((size_t)BHc * Tc * DKc * 2);
    unsigned short* Kb  = (unsigned short*)take((size_t)BHc * Tc * DKc * 2);
    unsigned short* Vt  = (unsigned short*)take((size_t)BHc * Tc * DKc * 2);
    unsigned short* Xb  = (unsigned short*)take((size_t)Mc * Dc * 2);
    unsigned short* An  = Xb;  // alias: Xb dead after qkv_gemm

    hipMemsetAsync(cnt, 0, 4096, stream);
    xconv_kernel<<<dim3((Mc * Dc) / (256 * 8)), dim3(256), 0, stream>>>(x, Xb);
    wtrans_kernel<<<dim3(Dc / 64, (Nqkv + Dc) / 64), dim3(256), 0, stream>>>(W_qkv, W_proj, WqT, WpT);
    qkv_gemm_kernel<<<dim3(Mc / 128, Nqkv / 128), dim3(256), 0, stream>>>(Xb, WqT, b_qkv, Qb, Kb, Vt);
    attn_kernel<<<dim3(NITEMS), dim3(256), 0, stream>>>(Qb, Kb, Vt, An, cnt);
    proj_gemm_kernel<<<dim3(Mc / 128, Dc / 64), dim3(256), 0, stream>>>(An, WpT, b_proj, out);
}